// Round 1
// baseline (24.766 us; speedup 1.0000x reference)
//
#include <hip/hip_runtime.h>

// Sparsemax over B=16384 equal segments of L=1024 contiguous fp32 elements.
// One 64-lane wave per segment; 16 elements/lane in registers; tau found by
// Michelot/Newton active-set iteration (no sort, no LDS, no barriers).

#define SEG_LEN 1024

__global__ __launch_bounds__(256) void sparsemax_wave_kernel(
    const float* __restrict__ x, float* __restrict__ out, int nseg) {
  const int gwave = (int)((blockIdx.x * blockDim.x + threadIdx.x) >> 6);
  const int lane  = (int)(threadIdx.x & 63);
  if (gwave >= nseg) return;

  const float4* __restrict__ xin =
      reinterpret_cast<const float4*>(x + (size_t)gwave * SEG_LEN);

  // Load 16 elements as 4 x float4, coalesced: lane l takes float4 index j*64+l.
  float4 v[4];
#pragma unroll
  for (int j = 0; j < 4; ++j) v[j] = xin[j * 64 + lane];

  // Segment max (per-lane then wave butterfly).
  float m = fmaxf(fmaxf(v[0].x, v[0].y), fmaxf(v[0].z, v[0].w));
#pragma unroll
  for (int j = 1; j < 4; ++j)
    m = fmaxf(m, fmaxf(fmaxf(v[j].x, v[j].y), fmaxf(v[j].z, v[j].w)));
#pragma unroll
  for (int off = 1; off < 64; off <<= 1)
    m = fmaxf(m, __shfl_xor(m, off));

  // Shift: xs = x - max  (xs <= 0, max element exactly 0).
  float xs[16];
#pragma unroll
  for (int j = 0; j < 4; ++j) {
    xs[j * 4 + 0] = v[j].x - m;
    xs[j * 4 + 1] = v[j].y - m;
    xs[j * 4 + 2] = v[j].z - m;
    xs[j * 4 + 3] = v[j].w - m;
  }

  // Newton / Michelot iteration on f(tau) = sum(max(xs - tau, 0)) = 1.
  // tau0 = -1 guarantees f(tau0) >= 1 -> monotone convergence from below.
  float tau = -1.0f;
  for (int it = 0; it < 32; ++it) {
    float s = 0.0f, c = 0.0f;
#pragma unroll
    for (int e = 0; e < 16; ++e) {
      const bool act = xs[e] > tau;
      s += act ? xs[e] : 0.0f;
      c += act ? 1.0f : 0.0f;
    }
#pragma unroll
    for (int off = 1; off < 64; off <<= 1) {
      s += __shfl_xor(s, off);
      c += __shfl_xor(c, off);
    }
    const float tn = (s - 1.0f) / c;  // c >= 1 always (max elem active, tn < 0)
    if (tn == tau) break;             // wave-uniform condition
    tau = tn;
  }

  // out = max(xs - tau, 0), coalesced float4 stores.
  float4* __restrict__ o =
      reinterpret_cast<float4*>(out + (size_t)gwave * SEG_LEN);
#pragma unroll
  for (int j = 0; j < 4; ++j) {
    float4 w;
    w.x = fmaxf(xs[j * 4 + 0] - tau, 0.0f);
    w.y = fmaxf(xs[j * 4 + 1] - tau, 0.0f);
    w.z = fmaxf(xs[j * 4 + 2] - tau, 0.0f);
    w.w = fmaxf(xs[j * 4 + 3] - tau, 0.0f);
    o[j * 64 + lane] = w;
  }
}

extern "C" void kernel_launch(void* const* d_in, const int* in_sizes, int n_in,
                              void* d_out, int out_size, void* d_ws, size_t ws_size,
                              hipStream_t stream) {
  const float* x = (const float*)d_in[0];
  float* out = (float*)d_out;
  const int n = in_sizes[0];
  const int nseg = n / SEG_LEN;                 // 16384
  const int waves_per_block = 4;                // 256 threads
  const int blocks = (nseg + waves_per_block - 1) / waves_per_block;
  sparsemax_wave_kernel<<<blocks, 256, 0, stream>>>(x, out, nseg);
}

// Round 3
// 24.729 us; speedup vs baseline: 1.0015x; 1.0015x over previous
//
#include <hip/hip_runtime.h>

// Sparsemax over B=16384 equal segments of L=1024 contiguous fp32 elements.
// One 64-lane wave per segment; 16 elements/lane in registers; tau found by
// Michelot/Newton active-set iteration (no sort, no LDS, no barriers).
// Stores are non-temporal (global_store_dwordx4 ... nt): output is write-once,
// keep it from churning L2/L3 so the x read stream stays cache-resident.

#define SEG_LEN 1024

typedef float f32x4 __attribute__((ext_vector_type(4)));

__global__ __launch_bounds__(256) void sparsemax_wave_kernel(
    const float* __restrict__ x, float* __restrict__ out, int nseg) {
  const int gwave = (int)((blockIdx.x * blockDim.x + threadIdx.x) >> 6);
  const int lane  = (int)(threadIdx.x & 63);
  if (gwave >= nseg) return;

  const f32x4* __restrict__ xin =
      reinterpret_cast<const f32x4*>(x + (size_t)gwave * SEG_LEN);

  // Load 16 elements as 4 x float4, coalesced: lane l takes float4 index j*64+l.
  f32x4 v[4];
#pragma unroll
  for (int j = 0; j < 4; ++j) v[j] = xin[j * 64 + lane];

  // Segment max (per-lane then wave butterfly).
  float m = fmaxf(fmaxf(v[0].x, v[0].y), fmaxf(v[0].z, v[0].w));
#pragma unroll
  for (int j = 1; j < 4; ++j)
    m = fmaxf(m, fmaxf(fmaxf(v[j].x, v[j].y), fmaxf(v[j].z, v[j].w)));
#pragma unroll
  for (int off = 1; off < 64; off <<= 1)
    m = fmaxf(m, __shfl_xor(m, off));

  // Shift: xs = x - max  (xs <= 0, max element exactly 0).
  float xs[16];
#pragma unroll
  for (int j = 0; j < 4; ++j) {
    xs[j * 4 + 0] = v[j].x - m;
    xs[j * 4 + 1] = v[j].y - m;
    xs[j * 4 + 2] = v[j].z - m;
    xs[j * 4 + 3] = v[j].w - m;
  }

  // Newton / Michelot iteration on f(tau) = sum(max(xs - tau, 0)) = 1.
  // tau0 = -1 guarantees f(tau0) >= 1 -> monotone convergence from below.
  float tau = -1.0f;
  for (int it = 0; it < 32; ++it) {
    float s = 0.0f, c = 0.0f;
#pragma unroll
    for (int e = 0; e < 16; ++e) {
      const bool act = xs[e] > tau;
      s += act ? xs[e] : 0.0f;
      c += act ? 1.0f : 0.0f;
    }
#pragma unroll
    for (int off = 1; off < 64; off <<= 1) {
      s += __shfl_xor(s, off);
      c += __shfl_xor(c, off);
    }
    const float tn = (s - 1.0f) / c;  // c >= 1 always (max elem active, tn < 0)
    if (tn == tau) break;             // wave-uniform condition
    tau = tn;
  }

  // out = max(xs - tau, 0), coalesced non-temporal float4 stores.
  f32x4* __restrict__ o =
      reinterpret_cast<f32x4*>(out + (size_t)gwave * SEG_LEN);
#pragma unroll
  for (int j = 0; j < 4; ++j) {
    f32x4 w;
    w.x = fmaxf(xs[j * 4 + 0] - tau, 0.0f);
    w.y = fmaxf(xs[j * 4 + 1] - tau, 0.0f);
    w.z = fmaxf(xs[j * 4 + 2] - tau, 0.0f);
    w.w = fmaxf(xs[j * 4 + 3] - tau, 0.0f);
    __builtin_nontemporal_store(w, &o[j * 64 + lane]);
  }
}

extern "C" void kernel_launch(void* const* d_in, const int* in_sizes, int n_in,
                              void* d_out, int out_size, void* d_ws, size_t ws_size,
                              hipStream_t stream) {
  const float* x = (const float*)d_in[0];
  float* out = (float*)d_out;
  const int n = in_sizes[0];
  const int nseg = n / SEG_LEN;                 // 16384
  const int waves_per_block = 4;                // 256 threads
  const int blocks = (nseg + waves_per_block - 1) / waves_per_block;
  sparsemax_wave_kernel<<<blocks, 256, 0, stream>>>(x, out, nseg);
}

// Round 4
// 24.210 us; speedup vs baseline: 1.0230x; 1.0215x over previous
//
#include <hip/hip_runtime.h>

// Sparsemax over B=16384 equal segments of L=1024 contiguous fp32 elements.
// One 64-lane wave per segment; 16 elements/lane in registers.
// tau via Michelot active-set iteration. All wave reductions are DPP
// suffix-scans (pure VALU) + readlane; active-set count via ballot+popc
// (SALU pipe). Zero DS/LDS ops, no barriers. Non-temporal stores.

#define SEG_LEN 1024

typedef float f32x4 __attribute__((ext_vector_type(4)));

// DPP-assisted add: v += dpp(v). Invalid source lanes contribute 0 (identity).
template <int CTRL>
static __device__ __forceinline__ float dpp_add(float v) {
  int d = __builtin_amdgcn_update_dpp(0, __float_as_int(v), CTRL, 0xF, 0xF, true);
  return v + __int_as_float(d);
}

// DPP-assisted max: invalid source lanes read old = v (identity for max).
template <int CTRL>
static __device__ __forceinline__ float dpp_max(float v) {
  int iv = __float_as_int(v);
  int d = __builtin_amdgcn_update_dpp(iv, iv, CTRL, 0xF, 0xF, false);
  return fmaxf(v, __int_as_float(d));
}

// Full-wave sum -> lane 63 -> readlane (uniform, SGPR-resident).
static __device__ __forceinline__ float wave_sum(float v) {
  v = dpp_add<0x111>(v);  // row_shr:1
  v = dpp_add<0x112>(v);  // row_shr:2
  v = dpp_add<0x114>(v);  // row_shr:4
  v = dpp_add<0x118>(v);  // row_shr:8
  v = dpp_add<0x142>(v);  // row_bcast:15
  v = dpp_add<0x143>(v);  // row_bcast:31
  return __int_as_float(__builtin_amdgcn_readlane(__float_as_int(v), 63));
}

// Full-wave max -> lane 63 -> readlane.
static __device__ __forceinline__ float wave_max(float v) {
  v = dpp_max<0x111>(v);
  v = dpp_max<0x112>(v);
  v = dpp_max<0x114>(v);
  v = dpp_max<0x118>(v);
  v = dpp_max<0x142>(v);
  v = dpp_max<0x143>(v);
  return __int_as_float(__builtin_amdgcn_readlane(__float_as_int(v), 63));
}

__global__ __launch_bounds__(256) void sparsemax_wave_kernel(
    const float* __restrict__ x, float* __restrict__ out, int nseg) {
  const int gwave = (int)((blockIdx.x * blockDim.x + threadIdx.x) >> 6);
  const int lane  = (int)(threadIdx.x & 63);
  if (gwave >= nseg) return;

  const f32x4* __restrict__ xin =
      reinterpret_cast<const f32x4*>(x + (size_t)gwave * SEG_LEN);

  // 16 elements/lane as 4 x float4, coalesced.
  f32x4 v[4];
#pragma unroll
  for (int j = 0; j < 4; ++j) v[j] = xin[j * 64 + lane];

  // Segment max: per-lane tree then DPP wave-max (uniform result).
  float m = fmaxf(fmaxf(v[0].x, v[0].y), fmaxf(v[0].z, v[0].w));
#pragma unroll
  for (int j = 1; j < 4; ++j)
    m = fmaxf(m, fmaxf(fmaxf(v[j].x, v[j].y), fmaxf(v[j].z, v[j].w)));
  m = wave_max(m);

  // Shift: xs = x - max  (xs <= 0, max element exactly 0).
  float xs[16];
#pragma unroll
  for (int j = 0; j < 4; ++j) {
    xs[j * 4 + 0] = v[j].x - m;
    xs[j * 4 + 1] = v[j].y - m;
    xs[j * 4 + 2] = v[j].z - m;
    xs[j * 4 + 3] = v[j].w - m;
  }

  // Michelot: tau_{k+1} = tau_k + (sum(max(xs-tau,0)) - 1)/|A_k|.
  // tau0 = -1 -> f(tau0) >= 1 (max elem contributes exactly 1), tau increases
  // monotonically, active set shrinks monotonically -> count-stable => done.
  float tau = -1.0f;
  int cprev = -1;
  for (int it = 0; it < 32; ++it) {
    float S = 0.0f;
    int cnt = 0;
#pragma unroll
    for (int e = 0; e < 16; ++e) {
      const float t = xs[e] - tau;
      S += fmaxf(t, 0.0f);
      cnt += (int)__popcll(__ballot(t > 0.0f));  // wave-total, SALU pipe
    }
    S = wave_sum(S);
    tau = tau + (S - 1.0f) * __builtin_amdgcn_rcpf((float)cnt);
    if (cnt == cprev) break;  // active set stable -> tau exact for that set
    cprev = cnt;
  }

  // out = max(xs - tau, 0), coalesced non-temporal float4 stores.
  f32x4* __restrict__ o =
      reinterpret_cast<f32x4*>(out + (size_t)gwave * SEG_LEN);
#pragma unroll
  for (int j = 0; j < 4; ++j) {
    f32x4 w;
    w.x = fmaxf(xs[j * 4 + 0] - tau, 0.0f);
    w.y = fmaxf(xs[j * 4 + 1] - tau, 0.0f);
    w.z = fmaxf(xs[j * 4 + 2] - tau, 0.0f);
    w.w = fmaxf(xs[j * 4 + 3] - tau, 0.0f);
    __builtin_nontemporal_store(w, &o[j * 64 + lane]);
  }
}

extern "C" void kernel_launch(void* const* d_in, const int* in_sizes, int n_in,
                              void* d_out, int out_size, void* d_ws, size_t ws_size,
                              hipStream_t stream) {
  const float* x = (const float*)d_in[0];
  float* out = (float*)d_out;
  const int n = in_sizes[0];
  const int nseg = n / SEG_LEN;                 // 16384
  const int waves_per_block = 4;                // 256 threads
  const int blocks = (nseg + waves_per_block - 1) / waves_per_block;
  sparsemax_wave_kernel<<<blocks, 256, 0, stream>>>(x, out, nseg);
}